// Round 8
// baseline (102.262 us; speedup 1.0000x reference)
//
#include <hip/hip_runtime.h>
#include <hip/hip_bf16.h>
#include <stdint.h>
#include <math.h>

#define NROWS 8192
#define DIM   256          // elements per row; fp8 -> 256 B per row
#define RB    256          // row bytes (fp8)
#define BI    128          // i rows per block (B operand, register-resident frags)
#define JSUB  64           // j rows per sub-tile (A operand, LDS double-buffered)
#define NBJS  8            // sub-tiles per block
#define JBLK  (JSUB*NBJS)  // 512 j rows per block
#define NG    (NROWS/JBLK) // 16 j-groups
#define NIT   (NROWS/BI)   // 64 i-tiles

typedef __attribute__((ext_vector_type(4)))  int   int4v;
typedef __attribute__((ext_vector_type(8)))  int   int8v;
typedef __attribute__((ext_vector_type(16))) float floatx16;

typedef const __attribute__((address_space(1))) uint32_t gas_u32;
typedef __attribute__((address_space(3))) uint32_t las_u32;

#define SCALE_1_16 0x7B7B7B7B          // E8M0 123 = 2^-4 in every byte
#define L2E10      14.4269504088896f   // 10 * log2(e)

__device__ __forceinline__ void gload_lds16(const void* g, void* l) {
    // LDS dest = wave-uniform base + lane*16 ; global src per-lane
    __builtin_amdgcn_global_load_lds((gas_u32*)(uintptr_t)g,
                                     (las_u32*)(uintptr_t)l, 16, 0, 0);
}

// ------------- Kernel 1: row-normalize fp32 -> fp8 e4m3 (x16); also zero d_out -------------
__global__ __launch_bounds__(256) void normalize_kernel(const float* __restrict__ emb,
                                                        uint32_t* __restrict__ e8,
                                                        float* __restrict__ out)
{
    if (blockIdx.x == 0 && threadIdx.x == 0) *out = 0.f;   // replaces memset dispatch
    int row  = blockIdx.x * 4 + (threadIdx.x >> 6);
    int lane = threadIdx.x & 63;
    const float4* rowp = (const float4*)(emb + (size_t)row * DIM);
    float4 v = rowp[lane];
    float ss = v.x*v.x + v.y*v.y + v.z*v.z + v.w*v.w;
    #pragma unroll
    for (int off = 32; off > 0; off >>= 1)
        ss += __shfl_xor(ss, off, 64);
    // store e * 16 in e4m3; MFMA scales (2^-4 per operand) remove the 2^8
    float inv = 16.0f / fmaxf(sqrtf(ss), 1e-8f);
    int r = __builtin_amdgcn_cvt_pk_fp8_f32(v.x * inv, v.y * inv, 0, false);
    r     = __builtin_amdgcn_cvt_pk_fp8_f32(v.z * inv, v.w * inv, r, true);
    e8[(size_t)row * (DIM / 4) + lane] = (uint32_t)r;
}

// ------------- Kernel 2: B-in-regs, A-streamed MX-fp8 32x32x64, 4 waves/SIMD -------------
// Wave tile per sub-tile: 64j x 32i (2 jt x 1 it); each lane owns exactly one i (col).
template<bool DIAG>
__device__ __forceinline__ void epi(const floatx16 acc[2],
                                    const int* __restrict__ tgt,
                                    int jbs, int h, int ic0, int tiv0,
                                    float& ps, float& ts)
{
    #pragma unroll
    for (int jt = 0; jt < 2; ++jt) {
        #pragma unroll
        for (int rq = 0; rq < 4; ++rq) {
            const int jg_ = jbs + jt * 32 + rq * 8 + h * 4;  // + r2 (0..3)
            const int4v t4 = *(const int4v*)(tgt + jg_);     // 4 consecutive j-targets
            #pragma unroll
            for (int r2 = 0; r2 < 4; ++r2) {
                float v = exp2f(fmaf(L2E10, acc[jt][rq * 4 + r2], -L2E10));
                if (DIAG) {
                    if (jg_ + r2 == ic0) v = 0.f;            // exclude diagonal
                }
                ts += v;
                ps += (t4[r2] == tiv0) ? v : 0.f;
            }
        }
    }
}

__global__ __launch_bounds__(256, 4) void tile_kernel(const uint8_t* __restrict__ e8,
                                                      const int* __restrict__ tgt,
                                                      float* __restrict__ pps,
                                                      float* __restrict__ pts)
{
    __shared__ uint8_t buf[2][JSUB * RB];   // 2 x 16 KB A double-buffer (only LDS use)

    const int bi   = blockIdx.x;
    const int jg   = blockIdx.y;
    const int tid  = threadIdx.x;
    const int wave = tid >> 6;
    const int lane = tid & 63;
    const int col  = lane & 31;        // MFMA row/col within 32 == this lane's i (local)
    const int h    = lane >> 5;        // K-half select

    // ---- B fragments straight from global to registers (once per block) ----
    // lane holds B row (wave*32+col), k-bytes [s*64 + h*32, +32) per s -- f8f6f4 layout
    const uint8_t* pb = e8 + (size_t)(bi * BI + wave * 32 + col) * RB + h * 32;
    int8v bfr[4];
    #pragma unroll
    for (int s = 0; s < 4; ++s)
        bfr[s] = *(const int8v*)(pb + s * 64);

    // ---- A staging map (mod-16 xor swizzle on 16B chunks of 256B rows) ----
    int goffA[4];
    #pragma unroll
    for (int t = 0; t < 4; ++t) {
        int s   = wave * 256 + t * 64 + lane;
        int row = s >> 4;
        int lc  = (s & 15) ^ (row & 15);
        goffA[t] = row * RB + lc * 16;
    }
    const char* gA = (const char*)(e8 + (size_t)jg * JBLK * RB);

    // boot: stage A sub-tile 0 -> buf[0]
    #pragma unroll
    for (int t = 0; t < 4; ++t)
        gload_lds16(gA + goffA[t], buf[0] + wave * 4096 + t * 1024);

    const int ic0  = bi * BI + wave * 32 + col;   // this lane's i
    const int tiv0 = tgt[ic0];

    // fragment phys-chunk base offsets: logical chunk s*4+h*2, xor (row&15)=(col&15)
    const int xm = col & 15;
    int poff[4];
    #pragma unroll
    for (int s = 0; s < 4; ++s)
        poff[s] = ((s * 4 + h * 2) ^ xm) << 4;    // partner chunk = poff[s]^16

    __syncthreads();   // drains A0 DMA

    float ps = 0.f, ts = 0.f;
    const int dpair = bi - jg * 4;   // sub-tile pair index touching the diagonal (if 0..3)

    #pragma unroll
    for (int bjs = 0; bjs < NBJS; ++bjs) {
        // issue next A stage into the other buffer; drains at this phase's end barrier,
        // i.e. AFTER this sub-tile's MFMAs + epilogue -> fully overlapped
        if (bjs < NBJS - 1) {
            const char* gAn = gA + (size_t)(bjs + 1) * JSUB * RB;
            #pragma unroll
            for (int t = 0; t < 4; ++t)
                gload_lds16(gAn + goffA[t], buf[(bjs + 1) & 1] + wave * 4096 + t * 1024);
        }

        const uint8_t* ab = buf[bjs & 1];
        floatx16 acc[2];
        #pragma unroll
        for (int jt = 0; jt < 2; ++jt)
            acc[jt] = (floatx16){0.f,0.f,0.f,0.f,0.f,0.f,0.f,0.f,
                                 0.f,0.f,0.f,0.f,0.f,0.f,0.f,0.f};

        #pragma unroll
        for (int s = 0; s < 4; ++s) {
            int8v af[2];
            #pragma unroll
            for (int jt = 0; jt < 2; ++jt) {
                const uint8_t* pa = ab + (jt * 32 + col) * RB;
                int4v lo = *(const int4v*)(pa + poff[s]);
                int4v hi = *(const int4v*)(pa + (poff[s] ^ 16));
                af[jt] = __builtin_shufflevector(lo, hi, 0, 1, 2, 3, 4, 5, 6, 7);
            }
            #pragma unroll
            for (int jt = 0; jt < 2; ++jt)
                acc[jt] = __builtin_amdgcn_mfma_scale_f32_32x32x64_f8f6f4(
                    af[jt], bfr[s], acc[jt], 0, 0,
                    0, SCALE_1_16, 0, SCALE_1_16);
        }

        // fused epilogue for this sub-tile (regs + broadcast tgt loads only)
        const int jbs = jg * JBLK + bjs * JSUB;
        if ((bjs >> 1) == dpair)
            epi<true >(acc, tgt, jbs, h, ic0, tiv0, ps, ts);
        else
            epi<false>(acc, tgt, jbs, h, ic0, tiv0, ps, ts);

        if (bjs < NBJS - 1)
            __syncthreads();   // single barrier per phase: drains next-A DMA,
                               // guards restage of the buffer just read
    }

    // lanes L and L+32 hold the same i with disjoint j-halves
    ps += __shfl_xor(ps, 32, 64);
    ts += __shfl_xor(ts, 32, 64);
    if (h == 0) {
        const size_t base = (size_t)jg * NROWS;
        pps[base + ic0] = ps;
        pts[base + ic0] = ts;
    }
}

// ------------- Kernel 3: per-row log-diff + global sum -------------
__global__ __launch_bounds__(256) void finalize_kernel(const float* __restrict__ pps,
                                                       const float* __restrict__ pts,
                                                       float* __restrict__ out)
{
    const int i = blockIdx.x * 256 + threadIdx.x;
    float sp = 0.f, st = 0.f;
    #pragma unroll
    for (int t = 0; t < NG; ++t) {
        sp += pps[(size_t)t * NROWS + i];
        st += pts[(size_t)t * NROWS + i];
    }
    float ns = st - sp;                 // negatives = total - positives (diag excluded in both)
    float loss = logf(ns) - logf(sp);   // fixed +10 shifts cancel
    #pragma unroll
    for (int off = 32; off > 0; off >>= 1)
        loss += __shfl_xor(loss, off, 64);
    __shared__ float w4[4];
    if ((threadIdx.x & 63) == 0) w4[threadIdx.x >> 6] = loss;
    __syncthreads();
    if (threadIdx.x == 0)
        atomicAdd(out, w4[0] + w4[1] + w4[2] + w4[3]);
}

extern "C" void kernel_launch(void* const* d_in, const int* in_sizes, int n_in,
                              void* d_out, int out_size, void* d_ws, size_t ws_size,
                              hipStream_t stream)
{
    (void)in_sizes; (void)n_in; (void)out_size; (void)ws_size;
    const float* emb = (const float*)d_in[0];
    const int*   tgt = (const int*)d_in[1];
    float*       out = (float*)d_out;

    uint32_t* e8  = (uint32_t*)d_ws;                                  // 2 MB fp8 rows
    float*    pps = (float*)((char*)d_ws + (size_t)NROWS * RB);       // 512 KB
    float*    pts = pps + (size_t)NG * NROWS;                         // 512 KB

    normalize_kernel<<<NROWS / 4, 256, 0, stream>>>(emb, e8, out);

    dim3 grid(NIT, NG);
    tile_kernel<<<grid, 256, 0, stream>>>((const uint8_t*)e8, tgt, pps, pts);

    finalize_kernel<<<NROWS / 256, 256, 0, stream>>>(pps, pts, out);
}

// Round 9
// 98.612 us; speedup vs baseline: 1.0370x; 1.0370x over previous
//
#include <hip/hip_runtime.h>
#include <hip/hip_bf16.h>
#include <stdint.h>
#include <math.h>

#define NROWS 8192
#define DIM   256          // elements per row; fp8 -> 256 B per row
#define RB    256          // row bytes (fp8)
#define BI    128          // i rows per block (B operand, register-resident frags)
#define JSUB  64           // j rows per sub-tile (A operand, LDS double-buffered)
#define NBJS  8            // sub-tiles per block
#define JBLK  (JSUB*NBJS)  // 512 j rows per block
#define NG    (NROWS/JBLK) // 16 j-groups
#define NIT   (NROWS/BI)   // 64 i-tiles
#define CAP   256          // max class members supported (mean 128, sd 11 -> safe)

typedef __attribute__((ext_vector_type(4)))  int   int4v;
typedef __attribute__((ext_vector_type(8)))  int   int8v;
typedef __attribute__((ext_vector_type(16))) float floatx16;

typedef const __attribute__((address_space(1))) uint32_t gas_u32;
typedef __attribute__((address_space(3))) uint32_t las_u32;

#define SCALE_1_16 0x7B7B7B7B          // E8M0 123 = 2^-4 in every byte
#define L2E10      14.4269504088896f   // 10 * log2(e)

#if __has_builtin(__builtin_amdgcn_exp2f)
#define EXP2(x) __builtin_amdgcn_exp2f(x)   // raw v_exp_f32; inputs in [-29,0] are safe
#else
#define EXP2(x) exp2f(x)
#endif

__device__ __forceinline__ void gload_lds16(const void* g, void* l) {
    // LDS dest = wave-uniform base + lane*16 ; global src per-lane
    __builtin_amdgcn_global_load_lds((gas_u32*)(uintptr_t)g,
                                     (las_u32*)(uintptr_t)l, 16, 0, 0);
}

// ------------- Kernel 1: row-normalize fp32 -> fp8 e4m3 (x16); also zero d_out -------------
__global__ __launch_bounds__(256) void normalize_kernel(const float* __restrict__ emb,
                                                        uint32_t* __restrict__ e8,
                                                        float* __restrict__ out)
{
    if (blockIdx.x == 0 && threadIdx.x == 0) *out = 0.f;   // replaces memset dispatch
    int row  = blockIdx.x * 4 + (threadIdx.x >> 6);
    int lane = threadIdx.x & 63;
    const float4* rowp = (const float4*)(emb + (size_t)row * DIM);
    float4 v = rowp[lane];
    float ss = v.x*v.x + v.y*v.y + v.z*v.z + v.w*v.w;
    #pragma unroll
    for (int off = 32; off > 0; off >>= 1)
        ss += __shfl_xor(ss, off, 64);
    // store e * 16 in e4m3; MFMA scales (2^-4 per operand) remove the 2^8
    float inv = 16.0f / fmaxf(sqrtf(ss), 1e-8f);
    int r = __builtin_amdgcn_cvt_pk_fp8_f32(v.x * inv, v.y * inv, 0, false);
    r     = __builtin_amdgcn_cvt_pk_fp8_f32(v.z * inv, v.w * inv, r, true);
    e8[(size_t)row * (DIM / 4) + lane] = (uint32_t)r;
}

// ------------- Kernel 2: per-class positives -> sp[i] (complete) -------------
// One block per class: gather member rows, Gram via MX-fp8 MFMA, exact diag/pad masking.
__global__ __launch_bounds__(256) void pos_kernel(const uint8_t* __restrict__ e8,
                                                  const int* __restrict__ tgt,
                                                  float* __restrict__ sp)
{
    __shared__ uint8_t rows[CAP * RB];   // 64 KB gathered member rows (xor-swizzled chunks)
    __shared__ int idx[CAP];
    __shared__ int cnt;

    const int c    = blockIdx.x;
    const int tid  = threadIdx.x;
    const int wave = tid >> 6;
    const int lane = tid & 63;
    const int col  = lane & 31;
    const int h    = lane >> 5;

    if (tid == 0) cnt = 0;
    __syncthreads();
    // scan targets, collect member indices (order irrelevant)
    for (int base = 0; base < NROWS; base += 256) {
        int j = base + tid;
        if (tgt[j] == c) {
            int p = atomicAdd(&cnt, 1);
            if (p < CAP) idx[p] = j;
        }
    }
    __syncthreads();
    const int M  = min(cnt, CAP);
    const int Mp = (M + 31) & ~31;

    // gather member rows via DMA: slot s -> row s>>4, phys chunk s&15,
    // logical chunk (s&15)^(row&15)  (same swizzle as the big kernel)
    const int nslots = M * 16;
    for (int g = wave; g * 64 < nslots; g += 4) {
        int s  = g * 64 + lane;
        int r  = s >> 4;
        int rc = min(r, M - 1);             // clamp tail; pad region overwritten below
        int lc = (s & 15) ^ (r & 15);
        gload_lds16(e8 + (size_t)idx[rc] * RB + lc * 16, rows + g * 1024);
    }
    __syncthreads();                        // drains DMA
    // zero pad rows [M, Mp)
    for (int s = M * 16 + tid; s < Mp * 16; s += 256)
        *(int4v*)(rows + (size_t)s * 16) = (int4v){0, 0, 0, 0};
    __syncthreads();

    // fragment phys-chunk offsets (same scheme as big kernel)
    const int xm = col & 15;
    int poff[4];
    #pragma unroll
    for (int s = 0; s < 4; ++s)
        poff[s] = ((s * 4 + h * 2) ^ xm) << 4;

    // lane owns member b = bt*32+col; accumulate over all a
    for (int bt = wave; bt * 32 < Mp; bt += 4) {
        const int b = bt * 32 + col;
        const uint8_t* pb = rows + (size_t)b * RB;
        int8v bfr[4];
        #pragma unroll
        for (int s = 0; s < 4; ++s) {
            int4v lo = *(const int4v*)(pb + poff[s]);
            int4v hi = *(const int4v*)(pb + (poff[s] ^ 16));
            bfr[s] = __builtin_shufflevector(lo, hi, 0, 1, 2, 3, 4, 5, 6, 7);
        }
        float psum = 0.f;
        for (int at = 0; at * 32 < Mp; ++at) {
            const uint8_t* pa = rows + (size_t)(at * 32 + col) * RB;
            floatx16 acc = (floatx16){0.f,0.f,0.f,0.f,0.f,0.f,0.f,0.f,
                                      0.f,0.f,0.f,0.f,0.f,0.f,0.f,0.f};
            #pragma unroll
            for (int s = 0; s < 4; ++s) {
                int4v lo = *(const int4v*)(pa + poff[s]);
                int4v hi = *(const int4v*)(pa + (poff[s] ^ 16));
                int8v af = __builtin_shufflevector(lo, hi, 0, 1, 2, 3, 4, 5, 6, 7);
                acc = __builtin_amdgcn_mfma_scale_f32_32x32x64_f8f6f4(
                    af, bfr[s], acc, 0, 0, 0, SCALE_1_16, 0, SCALE_1_16);
            }
            #pragma unroll
            for (int rq = 0; rq < 4; ++rq)
                #pragma unroll
                for (int r2 = 0; r2 < 4; ++r2) {
                    const int a = at * 32 + rq * 8 + h * 4 + r2;
                    float v = EXP2(fmaf(L2E10, acc[rq * 4 + r2], -L2E10));
                    psum += (a != b && a < M) ? v : 0.f;   // exact diag/pad mask
                }
        }
        psum += __shfl_xor(psum, 32, 64);   // h-halves hold disjoint a's for same b
        if (h == 0 && b < M) sp[idx[b]] = psum;
    }
}

// ------------- Kernel 3: B-in-regs, A-streamed MX-fp8 32x32x64, ts only -------------
// Wave tile per sub-tile: 64j x 32i; each lane owns one i (col). Epilogue: 3 VALU/element.
template<bool DIAG>
__device__ __forceinline__ void epi(const floatx16 acc[2],
                                    int jbs, int h, int ic0, float& ts)
{
    #pragma unroll
    for (int jt = 0; jt < 2; ++jt)
        #pragma unroll
        for (int rq = 0; rq < 4; ++rq)
            #pragma unroll
            for (int r2 = 0; r2 < 4; ++r2) {
                float v = EXP2(fmaf(L2E10, acc[jt][rq * 4 + r2], -L2E10));
                if (DIAG) {
                    const int jg_ = jbs + jt * 32 + rq * 8 + h * 4 + r2;
                    if (jg_ == ic0) v = 0.f;   // exclude diagonal
                }
                ts += v;
            }
}

__global__ __launch_bounds__(256, 4) void tile_kernel(const uint8_t* __restrict__ e8,
                                                      float* __restrict__ pts)
{
    __shared__ uint8_t buf[2][JSUB * RB];   // 2 x 16 KB A double-buffer (only LDS use)

    const int bi   = blockIdx.x;
    const int jg   = blockIdx.y;
    const int tid  = threadIdx.x;
    const int wave = tid >> 6;
    const int lane = tid & 63;
    const int col  = lane & 31;
    const int h    = lane >> 5;

    // B fragments straight from global to registers, once per block (L2-hit)
    const uint8_t* pb = e8 + (size_t)(bi * BI + wave * 32 + col) * RB + h * 32;
    int8v bfr[4];
    #pragma unroll
    for (int s = 0; s < 4; ++s)
        bfr[s] = *(const int8v*)(pb + s * 64);

    // A staging map (mod-16 xor swizzle on 16B chunks of 256B rows)
    int goffA[4];
    #pragma unroll
    for (int t = 0; t < 4; ++t) {
        int s   = wave * 256 + t * 64 + lane;
        int row = s >> 4;
        int lc  = (s & 15) ^ (row & 15);
        goffA[t] = row * RB + lc * 16;
    }
    const char* gA = (const char*)(e8 + (size_t)jg * JBLK * RB);

    // boot: stage A sub-tile 0 -> buf[0]
    #pragma unroll
    for (int t = 0; t < 4; ++t)
        gload_lds16(gA + goffA[t], buf[0] + wave * 4096 + t * 1024);

    const int ic0 = bi * BI + wave * 32 + col;   // this lane's i

    const int xm = col & 15;
    int poff[4];
    #pragma unroll
    for (int s = 0; s < 4; ++s)
        poff[s] = ((s * 4 + h * 2) ^ xm) << 4;   // partner chunk = poff[s]^16

    __syncthreads();   // drains A0 DMA

    float ts = 0.f;
    const int dpair = bi - jg * 4;   // sub-tile pair touching the diagonal (if 0..3)

    #pragma unroll
    for (int bjs = 0; bjs < NBJS; ++bjs) {
        // issue next A stage; drains at this phase's end barrier (fully overlapped)
        if (bjs < NBJS - 1) {
            const char* gAn = gA + (size_t)(bjs + 1) * JSUB * RB;
            #pragma unroll
            for (int t = 0; t < 4; ++t)
                gload_lds16(gAn + goffA[t], buf[(bjs + 1) & 1] + wave * 4096 + t * 1024);
        }

        const uint8_t* ab = buf[bjs & 1];
        floatx16 acc[2];
        #pragma unroll
        for (int jt = 0; jt < 2; ++jt)
            acc[jt] = (floatx16){0.f,0.f,0.f,0.f,0.f,0.f,0.f,0.f,
                                 0.f,0.f,0.f,0.f,0.f,0.f,0.f,0.f};

        #pragma unroll
        for (int s = 0; s < 4; ++s) {
            int8v af[2];
            #pragma unroll
            for (int jt = 0; jt < 2; ++jt) {
                const uint8_t* pa = ab + (size_t)(jt * 32 + col) * RB;
                int4v lo = *(const int4v*)(pa + poff[s]);
                int4v hi = *(const int4v*)(pa + (poff[s] ^ 16));
                af[jt] = __builtin_shufflevector(lo, hi, 0, 1, 2, 3, 4, 5, 6, 7);
            }
            #pragma unroll
            for (int jt = 0; jt < 2; ++jt)
                acc[jt] = __builtin_amdgcn_mfma_scale_f32_32x32x64_f8f6f4(
                    af[jt], bfr[s], acc[jt], 0, 0,
                    0, SCALE_1_16, 0, SCALE_1_16);
        }

        const int jbs = jg * JBLK + bjs * JSUB;
        if ((bjs >> 1) == dpair)
            epi<true >(acc, jbs, h, ic0, ts);
        else
            epi<false>(acc, jbs, h, ic0, ts);

        if (bjs < NBJS - 1)
            __syncthreads();   // single barrier per phase: drains next-A DMA,
                               // guards restage of the buffer just read
    }

    // lanes L and L+32 hold the same i with disjoint j-halves
    ts += __shfl_xor(ts, 32, 64);
    if (h == 0)
        pts[(size_t)jg * NROWS + ic0] = ts;
}

// ------------- Kernel 4: per-row log-diff + global sum -------------
__global__ __launch_bounds__(256) void finalize_kernel(const float* __restrict__ pts,
                                                       const float* __restrict__ sp,
                                                       float* __restrict__ out)
{
    const int i = blockIdx.x * 256 + threadIdx.x;
    float st = 0.f;
    #pragma unroll
    for (int t = 0; t < NG; ++t)
        st += pts[(size_t)t * NROWS + i];
    const float spv = sp[i];
    const float ns  = st - spv;           // negatives = total - positives (diag excluded)
    float loss = logf(ns) - logf(spv);    // fixed +10 shifts cancel
    #pragma unroll
    for (int off = 32; off > 0; off >>= 1)
        loss += __shfl_xor(loss, off, 64);
    __shared__ float w4[4];
    if ((threadIdx.x & 63) == 0) w4[threadIdx.x >> 6] = loss;
    __syncthreads();
    if (threadIdx.x == 0)
        atomicAdd(out, w4[0] + w4[1] + w4[2] + w4[3]);
}

extern "C" void kernel_launch(void* const* d_in, const int* in_sizes, int n_in,
                              void* d_out, int out_size, void* d_ws, size_t ws_size,
                              hipStream_t stream)
{
    (void)in_sizes; (void)n_in; (void)out_size; (void)ws_size;
    const float* emb = (const float*)d_in[0];
    const int*   tgt = (const int*)d_in[1];
    float*       out = (float*)d_out;

    uint32_t* e8  = (uint32_t*)d_ws;                                  // 2 MB fp8 rows
    float*    pts = (float*)((char*)d_ws + (size_t)NROWS * RB);       // 512 KB
    float*    sp  = pts + (size_t)NG * NROWS;                         // 32 KB

    normalize_kernel<<<NROWS / 4, 256, 0, stream>>>(emb, e8, out);

    pos_kernel<<<64, 256, 0, stream>>>((const uint8_t*)e8, tgt, sp);

    dim3 grid(NIT, NG);
    tile_kernel<<<grid, 256, 0, stream>>>((const uint8_t*)e8, pts);

    finalize_kernel<<<NROWS / 256, 256, 0, stream>>>(pts, sp, out);
}

// Round 10
// 83.007 us; speedup vs baseline: 1.2320x; 1.1880x over previous
//
#include <hip/hip_runtime.h>
#include <hip/hip_bf16.h>
#include <stdint.h>
#include <math.h>

#define NROWS 8192
#define DIM   256
#define RB    256          // row bytes (fp8)
#define BI    128          // i rows per tile block
#define JSUB  64           // j rows per sub-tile (LDS double-buffered)
#define NBJS  8
#define JBLK  (JSUB*NBJS)  // 512 j rows per tile block
#define NG    (NROWS/JBLK) // 16
#define NIT   (NROWS/BI)   // 64
#define NCLS  64
#define CAP   256          // max class members (mean 128)

typedef __attribute__((ext_vector_type(4)))  int   int4v;
typedef __attribute__((ext_vector_type(8)))  int   int8v;
typedef __attribute__((ext_vector_type(16))) float floatx16;

typedef const __attribute__((address_space(1))) uint32_t gas_u32;
typedef __attribute__((address_space(3))) uint32_t las_u32;

#define SCALE_1_16 0x7B7B7B7B          // E8M0 123 = 2^-4 in every byte
#define L2E10      14.4269504088896f   // 10 * log2(e)
#define CA_SCALE   (L2E10 * 16.0f)     // A-side fp8 pre-scale -> acc = L2E10*cos
#define CB_SCALE   16.0f               // B-side fp8 pre-scale

#if __has_builtin(__builtin_amdgcn_exp2f)
#define EXP2(x) __builtin_amdgcn_exp2f(x)   // raw v_exp_f32; inputs <= 14.43, safe
#else
#define EXP2(x) exp2f(x)
#endif

__device__ __forceinline__ void gload_lds16(const void* g, void* l) {
    // LDS dest = wave-uniform base + lane*16 ; global src per-lane
    __builtin_amdgcn_global_load_lds((gas_u32*)(uintptr_t)g,
                                     (las_u32*)(uintptr_t)l, 16, 0, 0);
}

// ---- Kernel 1: row-normalize fp32 -> two fp8 e4m3 arrays (A: x230.83, B: x16) ----
// acc = (CA*e_j)*(CB*e_i)*2^-8 = 14.4269*cos  -> epilogue needs no fma, no offset.
__global__ __launch_bounds__(256) void normalize_kernel(const float* __restrict__ emb,
                                                        uint32_t* __restrict__ a8,
                                                        uint32_t* __restrict__ b8,
                                                        float* __restrict__ out)
{
    if (blockIdx.x == 0 && threadIdx.x == 0) *out = 0.f;   // replaces memset dispatch
    int row  = blockIdx.x * 4 + (threadIdx.x >> 6);
    int lane = threadIdx.x & 63;
    float4 v = ((const float4*)(emb + (size_t)row * DIM))[lane];
    float ss = v.x*v.x + v.y*v.y + v.z*v.z + v.w*v.w;
    #pragma unroll
    for (int off = 32; off > 0; off >>= 1)
        ss += __shfl_xor(ss, off, 64);
    float inv = 1.0f / fmaxf(sqrtf(ss), 1e-8f);
    float ia = CA_SCALE * inv, ib = CB_SCALE * inv;
    int ra = __builtin_amdgcn_cvt_pk_fp8_f32(v.x * ia, v.y * ia, 0, false);
    ra     = __builtin_amdgcn_cvt_pk_fp8_f32(v.z * ia, v.w * ia, ra, true);
    int rb = __builtin_amdgcn_cvt_pk_fp8_f32(v.x * ib, v.y * ib, 0, false);
    rb     = __builtin_amdgcn_cvt_pk_fp8_f32(v.z * ib, v.w * ib, rb, true);
    a8[(size_t)row * 64 + lane] = (uint32_t)ra;
    b8[(size_t)row * 64 + lane] = (uint32_t)rb;
}

// ---- Kernel 2 (fused): blocks 0..63 = per-class positives; blocks 64+ = neg/total tiles ----
template<bool DIAG>
__device__ __forceinline__ void epi(const floatx16 acc[2],
                                    int jbs, int h, int ic0, float& ts)
{
    #pragma unroll
    for (int jt = 0; jt < 2; ++jt)
        #pragma unroll
        for (int rq = 0; rq < 4; ++rq)
            #pragma unroll
            for (int r2 = 0; r2 < 4; ++r2) {
                float v = EXP2(acc[jt][rq * 4 + r2]);   // acc already = L2E10*cos
                if (DIAG) {
                    const int jg_ = jbs + jt * 32 + rq * 8 + h * 4 + r2;
                    if (jg_ == ic0) v = 0.f;            // exclude diagonal
                }
                ts += v;
            }
}

__global__ __launch_bounds__(256, 4) void fused_kernel(const uint8_t* __restrict__ eA,
                                                       const uint8_t* __restrict__ eB,
                                                       const int* __restrict__ tgt,
                                                       float* __restrict__ pts,
                                                       float* __restrict__ sp)
{
    __shared__ uint8_t smem[2 * JSUB * RB];   // 32 KB: tile A dbuf / pos idx scratch

    const int tid  = threadIdx.x;
    const int wave = tid >> 6;
    const int lane = tid & 63;
    const int col  = lane & 31;
    const int h    = lane >> 5;

    if (blockIdx.x < NCLS) {
        // ================= positives path (one block per class) =================
        int* idx = (int*)smem;
        int* cnt = (int*)(smem + CAP * 4);
        const int c = blockIdx.x;
        if (tid == 0) *cnt = 0;
        __syncthreads();
        // scan all targets (coalesced int4 loads, batched for latency)
        int4v tv[8];
        #pragma unroll
        for (int k = 0; k < 8; ++k)
            tv[k] = *(const int4v*)(tgt + k * 1024 + tid * 4);
        #pragma unroll
        for (int k = 0; k < 8; ++k)
            #pragma unroll
            for (int r = 0; r < 4; ++r)
                if (tv[k][r] == c) {
                    int p = atomicAdd(cnt, 1);
                    if (p < CAP) idx[p] = k * 1024 + tid * 4 + r;
                }
        __syncthreads();
        const int M   = min(*cnt, CAP);
        const int Mp  = (M + 31) & ~31;
        const int nbt = Mp >> 5;

        // fragments straight from L2 (f8f6f4 layout: lane row=col, k [s*64+h*32,+32))
        for (int bt = wave; bt < nbt; bt += 4) {
            const int b = bt * 32 + col;
            const uint8_t* pb = eB + (size_t)idx[min(b, M - 1)] * RB + h * 32;
            int8v bfr[4];
            #pragma unroll
            for (int s = 0; s < 4; ++s)
                bfr[s] = *(const int8v*)(pb + s * 64);
            float psum = 0.f;
            for (int at = 0; at < nbt; ++at) {
                const uint8_t* pa = eA + (size_t)idx[min(at * 32 + col, M - 1)] * RB + h * 32;
                floatx16 acc = (floatx16){0.f,0.f,0.f,0.f,0.f,0.f,0.f,0.f,
                                          0.f,0.f,0.f,0.f,0.f,0.f,0.f,0.f};
                #pragma unroll
                for (int s = 0; s < 4; ++s) {
                    int8v af = *(const int8v*)(pa + s * 64);
                    acc = __builtin_amdgcn_mfma_scale_f32_32x32x64_f8f6f4(
                        af, bfr[s], acc, 0, 0, 0, SCALE_1_16, 0, SCALE_1_16);
                }
                #pragma unroll
                for (int rq = 0; rq < 4; ++rq)
                    #pragma unroll
                    for (int r2 = 0; r2 < 4; ++r2) {
                        const int a = at * 32 + rq * 8 + h * 4 + r2;
                        float v = EXP2(acc[rq * 4 + r2]);
                        psum += (a != b && a < M) ? v : 0.f;   // exact diag/pad mask
                    }
            }
            psum += __shfl_xor(psum, 32, 64);   // h-halves: disjoint a's, same b
            if (h == 0 && b < M) sp[idx[b]] = psum;
        }
        return;
    }

    // ================= negatives/total tile path =================
    const int g  = blockIdx.x - NCLS;
    const int bi = g & (NIT - 1);
    const int jg = g >> 6;

    // B fragments straight from global to registers, once per block (L2-hit)
    const uint8_t* pb = eB + (size_t)(bi * BI + wave * 32 + col) * RB + h * 32;
    int8v bfr[4];
    #pragma unroll
    for (int s = 0; s < 4; ++s)
        bfr[s] = *(const int8v*)(pb + s * 64);

    // A staging map (mod-16 xor swizzle on 16B chunks of 256B rows)
    int goffA[4];
    #pragma unroll
    for (int t = 0; t < 4; ++t) {
        int s   = wave * 256 + t * 64 + lane;
        int row = s >> 4;
        int lc  = (s & 15) ^ (row & 15);
        goffA[t] = row * RB + lc * 16;
    }
    const char* gA = (const char*)(eA + (size_t)jg * JBLK * RB);

    #pragma unroll
    for (int t = 0; t < 4; ++t)
        gload_lds16(gA + goffA[t], smem + wave * 4096 + t * 1024);

    const int ic0 = bi * BI + wave * 32 + col;   // this lane's i

    const int xm = col & 15;
    int poff[4];
    #pragma unroll
    for (int s = 0; s < 4; ++s)
        poff[s] = ((s * 4 + h * 2) ^ xm) << 4;   // partner chunk = poff[s]^16

    __syncthreads();   // drains A0 DMA

    float ts = 0.f;
    const int dpair = bi - jg * 4;   // sub-tile pair touching the diagonal (if 0..3)

    #pragma unroll
    for (int bjs = 0; bjs < NBJS; ++bjs) {
        if (bjs < NBJS - 1) {   // issue next A stage; drains at phase-end barrier
            const char* gAn = gA + (size_t)(bjs + 1) * JSUB * RB;
            #pragma unroll
            for (int t = 0; t < 4; ++t)
                gload_lds16(gAn + goffA[t],
                            smem + ((bjs + 1) & 1) * (JSUB * RB) + wave * 4096 + t * 1024);
        }

        const uint8_t* ab = smem + (bjs & 1) * (JSUB * RB);
        floatx16 acc[2];
        #pragma unroll
        for (int jt = 0; jt < 2; ++jt)
            acc[jt] = (floatx16){0.f,0.f,0.f,0.f,0.f,0.f,0.f,0.f,
                                 0.f,0.f,0.f,0.f,0.f,0.f,0.f,0.f};

        #pragma unroll
        for (int s = 0; s < 4; ++s) {
            int8v af[2];
            #pragma unroll
            for (int jt = 0; jt < 2; ++jt) {
                const uint8_t* pa = ab + (size_t)(jt * 32 + col) * RB;
                int4v lo = *(const int4v*)(pa + poff[s]);
                int4v hi = *(const int4v*)(pa + (poff[s] ^ 16));
                af[jt] = __builtin_shufflevector(lo, hi, 0, 1, 2, 3, 4, 5, 6, 7);
            }
            #pragma unroll
            for (int jt = 0; jt < 2; ++jt)
                acc[jt] = __builtin_amdgcn_mfma_scale_f32_32x32x64_f8f6f4(
                    af[jt], bfr[s], acc[jt], 0, 0,
                    0, SCALE_1_16, 0, SCALE_1_16);
        }

        const int jbs = jg * JBLK + bjs * JSUB;
        if ((bjs >> 1) == dpair)
            epi<true >(acc, jbs, h, ic0, ts);
        else
            epi<false>(acc, jbs, h, ic0, ts);

        if (bjs < NBJS - 1)
            __syncthreads();   // drains next-A DMA; guards restage of buffer just read
    }

    ts += __shfl_xor(ts, 32, 64);   // L and L+32: same i, disjoint j-halves
    if (h == 0)
        pts[(size_t)jg * NROWS + ic0] = ts;
}

// ---- Kernel 3: per-row log-diff + global sum ----
__global__ __launch_bounds__(256) void finalize_kernel(const float* __restrict__ pts,
                                                       const float* __restrict__ sp,
                                                       float* __restrict__ out)
{
    const int i = blockIdx.x * 256 + threadIdx.x;
    float st = 0.f;
    #pragma unroll
    for (int t = 0; t < NG; ++t)
        st += pts[(size_t)t * NROWS + i];
    const float spv = sp[i];
    const float ns  = st - spv;          // negatives = total - positives (diag-free both)
    float loss = logf(ns) - logf(spv);
    #pragma unroll
    for (int off = 32; off > 0; off >>= 1)
        loss += __shfl_xor(loss, off, 64);
    __shared__ float w4[4];
    if ((threadIdx.x & 63) == 0) w4[threadIdx.x >> 6] = loss;
    __syncthreads();
    if (threadIdx.x == 0)
        atomicAdd(out, w4[0] + w4[1] + w4[2] + w4[3]);
}

extern "C" void kernel_launch(void* const* d_in, const int* in_sizes, int n_in,
                              void* d_out, int out_size, void* d_ws, size_t ws_size,
                              hipStream_t stream)
{
    (void)in_sizes; (void)n_in; (void)out_size; (void)ws_size;
    const float* emb = (const float*)d_in[0];
    const int*   tgt = (const int*)d_in[1];
    float*       out = (float*)d_out;

    uint32_t* a8  = (uint32_t*)d_ws;                                  // 2 MB
    uint32_t* b8  = a8 + (size_t)NROWS * 64;                          // 2 MB
    float*    pts = (float*)(b8 + (size_t)NROWS * 64);                // 512 KB
    float*    sp  = pts + (size_t)NG * NROWS;                         // 32 KB

    normalize_kernel<<<NROWS / 4, 256, 0, stream>>>(emb, a8, b8, out);

    fused_kernel<<<NCLS + NIT * NG, 256, 0, stream>>>(
        (const uint8_t*)a8, (const uint8_t*)b8, tgt, pts, sp);

    finalize_kernel<<<NROWS / 256, 256, 0, stream>>>(pts, sp, out);
}